// Round 2
// baseline (2814.918 us; speedup 1.0000x reference)
//
#include <hip/hip_runtime.h>
#include <hip/hip_bf16.h>

// MAMBA2_2D: fused per-sequence kernel.
// Key algebra: flip(axis=0) passes are batch-axis flips of a batch-equivariant
// function -> h2==h1, v2==v1 exactly; only one mamba per direction needed.
// L=64 scan done as single-chunk quadratic form (G = C B^T once per sequence,
// per-head decay mask M, Y = M X); out_w/norm_w/fc fold into precomputed
// Wc (256x512 per direction); per-row RMS scalar applied after projection.
// OUTPUT IS FLOAT32 (reference computes in jnp.float32 throughout).

#define NTH 512
#define USTRIDE 65

__device__ __forceinline__ float bf2f(__hip_bfloat16 v){ return __bfloat162float(v); }
__device__ __forceinline__ __hip_bfloat16 f2bf(float v){ return __float2bfloat16(v); }
__device__ __forceinline__ float silu_f(float v){ return v / (1.f + __expf(-v)); }
__device__ __forceinline__ float softplus_f(float v){
  return fmaxf(v, 0.f) + log1pf(__expf(-fabsf(v)));
}

// out[t][p] (p = 0..NP*8-1) = sum_c u[t][c] * W[p*256 + c]
// sm_uT: fp32 [256][USTRIDE]; sm_wst: fp32 [NP*8][32] staging; out: fp32 [P][64] as out[p*64+t]
template<int NP>
__device__ __forceinline__ void u_gemm(const float* __restrict__ W,
                                       const float* sm_uT, float* sm_wst,
                                       float* out, int tid)
{
  const int t = tid & 63;
  const int w = tid >> 6;
  constexpr int P = NP * 8;
  float acc[NP];
#pragma unroll
  for (int i = 0; i < NP; ++i) acc[i] = 0.f;
  for (int ct = 0; ct < 8; ++ct) {
    __syncthreads();   // guard previous consumers of sm_wst/out regions
    for (int i = tid; i < P * 32; i += NTH) {
      int p = i >> 5, cc = i & 31;
      sm_wst[i] = W[p * 256 + ct * 32 + cc];
    }
    __syncthreads();
    float ur[32];
#pragma unroll
    for (int cc = 0; cc < 32; ++cc)
      ur[cc] = sm_uT[(ct * 32 + cc) * USTRIDE + t];
#pragma unroll
    for (int ii = 0; ii < NP; ++ii) {
      const float4* wp4 = (const float4*)(sm_wst + (w + ii * 8) * 32);
      float a = acc[ii];
#pragma unroll
      for (int q = 0; q < 8; ++q) {
        float4 wv = wp4[q];
        a += ur[q*4+0]*wv.x + ur[q*4+1]*wv.y + ur[q*4+2]*wv.z + ur[q*4+3]*wv.w;
      }
      acc[ii] = a;
    }
  }
#pragma unroll
  for (int ii = 0; ii < NP; ++ii) out[(w + ii * 8) * 64 + t] = acc[ii];
  // caller must __syncthreads() before reading out
}

// Wc[dir][o][j] = norm_w[j] * sum_k (fc_w[o][off+k] + fc_w[o][off+256+k]) * out_w[k][j]
__global__ void setup_wc(const float* __restrict__ fc_w,
                         const float* __restrict__ how, const float* __restrict__ hnw,
                         const float* __restrict__ vow, const float* __restrict__ vnw,
                         float* __restrict__ Wc)
{
  int id = blockIdx.x * blockDim.x + threadIdx.x;   // grid covers 262144
  if (id >= 262144) return;
  int dir = id >> 17;           // 0 = h (fc cols 512..1023), 1 = v (fc cols 0..511)
  int r = id & 131071;
  int o = r >> 9, j = r & 511;
  const float* ow = dir ? vow : how;
  const float* nw = dir ? vnw : hnw;
  int off = dir ? 0 : 512;
  const float* fr = fc_w + o * 1024 + off;
  float acc = 0.f;
  for (int k = 0; k < 256; ++k) acc += (fr[k] + fr[256 + k]) * ow[k * 512 + j];
  Wc[id] = nw[j] * acc;
}

// LDS float offsets
#define OFF_BC   16640   // bf16 [128][64]  (B then C), 4096 floats
#define OFF_DT   20736   // fp32 [8][64]
#define OFF_CUM  21248   // fp32 [8][64]
#define OFF_G    21760   // fp32 [s][t] 4096
#define OFF_SSQ  25856   // fp32 [64]
#define OFF_UN   25920   // union region, 14336 floats (57344 B)
#define SM_TOT   40256   // 161024 bytes

template<int DIR>
__global__ __launch_bounds__(NTH)
void mamba_dir_kernel(const float* __restrict__ x,
                      const float* __restrict__ in_w,
                      const float* __restrict__ conv_w,
                      const float* __restrict__ conv_b,
                      const float* __restrict__ dt_bias,
                      const float* __restrict__ A_log,
                      const float* __restrict__ Dvec,
                      const float* __restrict__ Wc,
                      const float* __restrict__ fc_b,
                      float* __restrict__ out)
{
  __shared__ float sm[SM_TOT];
  float* smU = sm;                                   // fp32 [256][USTRIDE]
  __hip_bfloat16* smBC = (__hip_bfloat16*)(sm + OFF_BC);
  float* smDT  = sm + OFF_DT;
  float* smCUM = sm + OFF_CUM;
  float* smG   = sm + OFF_G;
  float* smSSQ = sm + OFF_SSQ;
  float* smUN  = sm + OFF_UN;
  float* xh  = smUN;                                 // fp32 [64p][64t]
  float* smM = smUN + 4096;                          // fp32 [s][t]
  float* zh  = smUN + 8192;                          // fp32 [64j][64t]
  __hip_bfloat16* gh = (__hip_bfloat16*)(smUN + 12288); // bf16 [64j][64t]

  const int tid = threadIdx.x;
  const int t = tid & 63;
  const int w = tid >> 6;
  const int s = blockIdx.x;

  int ubase, ustride;
  if (DIR == 0) { ubase = s * 16384; ustride = 256; }
  else { ubase = (s >> 6) * 1048576 + (s & 63) * 256; ustride = 16384; }

  // ---- stage u (coalesced global, conflict-free transposed LDS store) ----
  for (int i = tid; i < 16384; i += NTH) {
    int tt = i >> 8, c = i & 255;
    smU[c * USTRIDE + tt] = x[ubase + tt * ustride + c];
  }
  if (tid < 64) smSSQ[tid] = 0.f;

  // ---- phase A: B,C,dt projection (in_w rows 1024..1159) ----
  u_gemm<17>(in_w + 1024 * 256, smU, smUN + 9216 /*wst*/, smUN /*raw [136][64]*/, tid);
  __syncthreads();

  {
    const float* raw = smUN;
    // conv + silu on the 128 B/C columns -> smBC (bf16)
    for (int ii = 0; ii < 16; ++ii) {
      int q = w + ii * 8;            // 0..127
      int ch = 512 + q;
      const float* base = raw + q * 64 + t;
      float v3 = base[0];
      float v2 = (t >= 1) ? base[-1] : 0.f;
      float v1 = (t >= 2) ? base[-2] : 0.f;
      float v0 = (t >= 3) ? base[-3] : 0.f;
      const float4 cw = *(const float4*)(conv_w + ch * 4);
      float v = cw.x*v0 + cw.y*v1 + cw.z*v2 + cw.w*v3 + conv_b[ch];
      smBC[q * 64 + t] = f2bf(silu_f(v));
    }
    // dt -> softplus, cum (wave w handles head w; lane = t)
    float dtv = softplus_f(raw[(128 + w) * 64 + t] + dt_bias[w]);
    smDT[w * 64 + t] = dtv;
    float cum = -__expf(A_log[w]) * dtv;
#pragma unroll
    for (int off = 1; off < 64; off <<= 1) {
      float y = __shfl_up(cum, off, 64);
      if (t >= off) cum += y;
    }
    smCUM[w * 64 + t] = cum;
  }
  __syncthreads();

  // ---- G[t][s] = sum_n C[t][n]*B[s][n], stored smG[s*64+t] ----
  {
    float acc[8];
#pragma unroll
    for (int ii = 0; ii < 8; ++ii) acc[ii] = 0.f;
    for (int n = 0; n < 64; ++n) {
      float cv = bf2f(smBC[(64 + n) * 64 + t]);
#pragma unroll
      for (int ii = 0; ii < 8; ++ii)
        acc[ii] += cv * bf2f(smBC[n * 64 + (w + ii * 8)]);
    }
#pragma unroll
    for (int ii = 0; ii < 8; ++ii) smG[(w + ii * 8) * 64 + t] = acc[ii];
  }
  // no explicit sync needed: next u_gemm starts with one

  float acc_o[32];                     // folded out-proj accumulators, o = w + ii*8
#pragma unroll
  for (int ii = 0; ii < 32; ++ii) acc_o[ii] = 0.f;

  for (int hd = 0; hd < 8; ++hd) {
    // D1: x head projection (zxbcdt cols 512+hd*64 ..)
    u_gemm<8>(in_w + (512 + hd * 64) * 256, smU, smM /*wst*/, xh, tid);
    __syncthreads();
    // conv + silu in place on xh
    {
      float r0[8], r1[8], r2[8], r3[8];
#pragma unroll
      for (int ii = 0; ii < 8; ++ii) {
        int p = w + ii * 8;
        const float* base = xh + p * 64 + t;
        r3[ii] = base[0];
        r2[ii] = (t >= 1) ? base[-1] : 0.f;
        r1[ii] = (t >= 2) ? base[-2] : 0.f;
        r0[ii] = (t >= 3) ? base[-3] : 0.f;
      }
      __syncthreads();
#pragma unroll
      for (int ii = 0; ii < 8; ++ii) {
        int p = w + ii * 8, ch = hd * 64 + p;
        const float4 cw = *(const float4*)(conv_w + ch * 4);
        float v = cw.x*r0[ii] + cw.y*r1[ii] + cw.z*r2[ii] + cw.w*r3[ii] + conv_b[ch];
        xh[p * 64 + t] = silu_f(v);
      }
    }
    // D2: M[t][s] = (t>=s) * exp(cum[t]-cum[s]) * dt[s] * G[t][s], stored [s][t]
    {
      const float* cumh = smCUM + hd * 64;
      const float* dth  = smDT + hd * 64;
      for (int idx = tid; idx < 4096; idx += NTH) {
        int ss = idx >> 6, tt = idx & 63;
        float m = 0.f;
        if (tt >= ss) m = __expf(cumh[tt] - cumh[ss]) * dth[ss] * smG[idx];
        smM[idx] = m;
      }
    }
    // D3: z head projection (zxbcdt cols hd*64 ..) ; wst uses gh spot (dead)
    u_gemm<8>(in_w + (hd * 64) * 256, smU, (float*)gh /*wst*/, zh, tid);
    __syncthreads();
    // D4: Y = M @ X, gate with silu(z), D-term, ssq, write gh (bf16)
    {
      float acc[8];
#pragma unroll
      for (int ii = 0; ii < 8; ++ii) acc[ii] = 0.f;
      for (int s4 = 0; s4 < 64; s4 += 4) {
        float m0 = smM[(s4 + 0) * 64 + t];
        float m1 = smM[(s4 + 1) * 64 + t];
        float m2 = smM[(s4 + 2) * 64 + t];
        float m3 = smM[(s4 + 3) * 64 + t];
#pragma unroll
        for (int ii = 0; ii < 8; ++ii) {
          const float4 xv = *(const float4*)(xh + (w + ii * 8) * 64 + s4);
          acc[ii] += m0*xv.x + m1*xv.y + m2*xv.z + m3*xv.w;
        }
      }
      float Dh = Dvec[hd];
      float part = 0.f;
#pragma unroll
      for (int ii = 0; ii < 8; ++ii) {
        int p = w + ii * 8;
        float yv = acc[ii] + Dh * xh[p * 64 + t];
        float zv = zh[p * 64 + t];
        float g = yv * silu_f(zv);
        part += g * g;
        gh[p * 64 + t] = f2bf(g);
      }
      atomicAdd(&smSSQ[t], part);
    }
    // D5: acc_o[o] += sum_j g[j] * Wc[o][hd*64+j]  (Wc staged fp32 [256][32])
    float* Wcc = smUN;
    for (int half = 0; half < 2; ++half) {
      __syncthreads();   // D4 done reading xh/M; gh written
      for (int i = tid; i < 8192; i += NTH) {
        int o = i >> 5, jj = i & 31;
        Wcc[i] = Wc[o * 512 + hd * 64 + half * 32 + jj];
      }
      __syncthreads();
#pragma unroll
      for (int jq = 0; jq < 8; ++jq) {
        int jb = half * 32 + jq * 4;
        float g0 = bf2f(gh[(jb + 0) * 64 + t]);
        float g1 = bf2f(gh[(jb + 1) * 64 + t]);
        float g2 = bf2f(gh[(jb + 2) * 64 + t]);
        float g3 = bf2f(gh[(jb + 3) * 64 + t]);
#pragma unroll
        for (int ii = 0; ii < 32; ++ii) {
          const float4 wv = *(const float4*)(Wcc + (w + ii * 8) * 32 + jq * 4);
          acc_o[ii] += g0*wv.x + g1*wv.y + g2*wv.z + g3*wv.w;
        }
      }
    }
  }

  // ---- epilogue: RMS factor, transpose-stage, coalesced fp32 writes ----
  __syncthreads();
  {
    float rms = 1.f / sqrtf(smSSQ[t] * (1.f / 512.f) + 1e-5f);
    float* stg = smUN;   // fp32 [64][USTRIDE]
    for (int oc = 0; oc < 4; ++oc) {
      __syncthreads();
#pragma unroll
      for (int k = 0; k < 8; ++k)
        stg[t * USTRIDE + w + k * 8] = rms * acc_o[oc * 8 + k];
      __syncthreads();
      for (int i = tid; i < 4096; i += NTH) {
        int tt = i >> 6, oo = i & 63;
        int row = (DIR == 0) ? (s * 64 + tt)
                             : ((s >> 6) * 4096 + tt * 64 + (s & 63));
        int gi = row * 256 + oc * 64 + oo;
        float val = stg[tt * USTRIDE + oo];
        if (DIR == 0) out[gi] = fc_b[oc * 64 + oo] + val;
        else          out[gi] += val;
      }
    }
  }
}

extern "C" void kernel_launch(void* const* d_in, const int* in_sizes, int n_in,
                              void* d_out, int out_size, void* d_ws, size_t ws_size,
                              hipStream_t stream) {
  const float* x          = (const float*)d_in[0];
  const float* mh_in_w    = (const float*)d_in[1];
  const float* mh_conv_w  = (const float*)d_in[2];
  const float* mh_conv_b  = (const float*)d_in[3];
  const float* mh_dt_bias = (const float*)d_in[4];
  const float* mh_A_log   = (const float*)d_in[5];
  const float* mh_D       = (const float*)d_in[6];
  const float* mh_norm_w  = (const float*)d_in[7];
  const float* mh_out_w   = (const float*)d_in[8];
  const float* mv_in_w    = (const float*)d_in[9];
  const float* mv_conv_w  = (const float*)d_in[10];
  const float* mv_conv_b  = (const float*)d_in[11];
  const float* mv_dt_bias = (const float*)d_in[12];
  const float* mv_A_log   = (const float*)d_in[13];
  const float* mv_D       = (const float*)d_in[14];
  const float* mv_norm_w  = (const float*)d_in[15];
  const float* mv_out_w   = (const float*)d_in[16];
  const float* fc_w       = (const float*)d_in[17];
  const float* fc_b       = (const float*)d_in[18];
  float* out = (float*)d_out;          // reference computes in float32
  float* Wc = (float*)d_ws;            // 2 * 131072 floats = 1 MB scratch

  setup_wc<<<1024, 256, 0, stream>>>(fc_w, mh_out_w, mh_norm_w, mv_out_w, mv_norm_w, Wc);
  mamba_dir_kernel<0><<<512, NTH, 0, stream>>>(x, mh_in_w, mh_conv_w, mh_conv_b,
      mh_dt_bias, mh_A_log, mh_D, Wc, fc_b, out);
  mamba_dir_kernel<1><<<512, NTH, 0, stream>>>(x, mv_in_w, mv_conv_w, mv_conv_b,
      mv_dt_bias, mv_A_log, mv_D, Wc + 131072, fc_b, out);
}

// Round 3
// 554.385 us; speedup vs baseline: 5.0775x; 5.0775x over previous
//
#include <hip/hip_runtime.h>
#include <hip/hip_bf16.h>

// MAMBA2_2D fused kernel, round 3: projection GEMMs (in-proj B/C/dt, per-head
// x/z, folded out-proj) moved to bf16 MFMA 16x16x32. Weights cast to bf16 in
// ws (in_w padded to 1168 rows); B-operand fragments loaded directly from
// global (L2-resident). G / M / Y=MX / conv / gating stay fp32 VALU as in the
// round-2 passing kernel. Output float32.

#define NTH 512

typedef __attribute__((ext_vector_type(8))) short short8;
typedef __attribute__((ext_vector_type(4))) float floatx4;

__device__ __forceinline__ float silu_f(float v){ return v / (1.f + __expf(-v)); }
__device__ __forceinline__ float softplus_f(float v){
  return fmaxf(v, 0.f) + log1pf(__expf(-fabsf(v)));
}
__device__ __forceinline__ short f2bs(float v){
  __hip_bfloat16 h = __float2bfloat16(v);
  return *reinterpret_cast<short*>(&h);
}
__device__ __forceinline__ float bs2f(short s){
  __hip_bfloat16 h = *reinterpret_cast<__hip_bfloat16*>(&s);
  return __bfloat162float(h);
}

// Wc[dir][o][j] = bf16( norm_w[j] * sum_k (fc[o][off+k]+fc[o][off+256+k]) * out_w[k][j] )
__global__ void setup_wc(const float* __restrict__ fc_w,
                         const float* __restrict__ how, const float* __restrict__ hnw,
                         const float* __restrict__ vow, const float* __restrict__ vnw,
                         __hip_bfloat16* __restrict__ Wc)
{
  int id = blockIdx.x * blockDim.x + threadIdx.x;
  if (id >= 262144) return;
  int dir = id >> 17;
  int r = id & 131071;
  int o = r >> 9, j = r & 511;
  const float* ow = dir ? vow : how;
  const float* nw = dir ? vnw : hnw;
  int off = dir ? 0 : 512;
  const float* fr = fc_w + o * 1024 + off;
  float acc = 0.f;
  for (int k = 0; k < 256; ++k) acc += (fr[k] + fr[256 + k]) * ow[k * 512 + j];
  Wc[id] = __float2bfloat16(nw[j] * acc);
}

// in_w fp32 [1160][256] -> bf16 [1168][256], rows 1160..1167 zero (dt tile pad)
__global__ void cast_inw(const float* __restrict__ hw, const float* __restrict__ vw,
                         __hip_bfloat16* __restrict__ dst)
{
  int id = blockIdx.x * blockDim.x + threadIdx.x;   // 2*1168*256 = 598016
  if (id >= 598016) return;
  int dir = id / 299008;
  int r = id % 299008;
  int row = r >> 8;
  const float* src = dir ? vw : hw;
  float v = (row < 1160) ? src[r] : 0.f;
  dst[id] = __float2bfloat16(v);
}

// LDS word offsets
#define OFF_RAW  8448    // fp32 [144][68] (BC+dt raw; unions with xh/zh)
#define OFF_XH   8448    // fp32 [64][68]
#define OFF_ZH   12800   // fp32 [64][68]
#define OFF_M    18240   // fp32 [64][64]  [s][t]
#define OFF_G    22336   // fp32 [64][64]  [s][t]
#define OFF_BCC  26432   // bf16 [128][64] [ch][t]
#define OFF_GB   30528   // bf16 [64][74]  [t][j]
#define OFF_DT   32896   // fp32 [8][64]
#define OFF_CUM  33408   // fp32 [8][64]
#define OFF_SSQ  33920   // fp32 [64]
#define OFF_RMS  33984   // fp32 [64]
#define SM_TOT   34048   // 136192 bytes

template<int DIR>
__global__ __launch_bounds__(NTH)
void mamba_dir_kernel(const float* __restrict__ x,
                      const __hip_bfloat16* __restrict__ inw_bf,  // [1168][256]
                      const float* __restrict__ conv_w,
                      const float* __restrict__ conv_b,
                      const float* __restrict__ dt_bias,
                      const float* __restrict__ A_log,
                      const float* __restrict__ Dvec,
                      const __hip_bfloat16* __restrict__ Wc,      // [256][512]
                      const float* __restrict__ fc_b,
                      float* __restrict__ out)
{
  __shared__ float sm[SM_TOT];
  short* smU  = (short*)sm;               // bf16 [64][264], row stride 528 B
  float* raw  = sm + OFF_RAW;
  float* xh   = sm + OFF_XH;
  float* zh   = sm + OFF_ZH;
  float* smM  = sm + OFF_M;
  float* smG  = sm + OFF_G;
  short* smBC = (short*)(sm + OFF_BCC);
  short* smg  = (short*)(sm + OFF_GB);
  float* smDT  = sm + OFF_DT;
  float* smCUM = sm + OFF_CUM;
  float* smSSQ = sm + OFF_SSQ;
  float* smRMS = sm + OFF_RMS;

  const int tid = threadIdx.x;
  const int t = tid & 63;
  const int w = tid >> 6;
  const int lane15 = tid & 15;
  const int quad = (tid & 63) >> 4;
  const int s = blockIdx.x;

  auto MF = [](short8 a, short8 b, floatx4 c) -> floatx4 {
    return __builtin_amdgcn_mfma_f32_16x16x32_bf16(a, b, c, 0, 0, 0);
  };
  // A-frag from staged u: A[m=lane15][k=quad*8+j]
  auto ldA_u = [&](int mt, int kt) -> short8 {
    int tt = mt * 16 + lane15;
    int kk = kt * 32 + quad * 8;
    return *(const short8*)(smU + tt * 264 + kk);   // 16B aligned
  };
  // B-frag from global bf16 weights, row-major [N][256]
  auto ldB_w = [&](int row0, int kt) -> short8 {
    return *(const short8*)((const short*)inw_bf + (row0 + lane15) * 256 + kt * 32 + quad * 8);
  };
  auto ldB_wc = [&](int o0, int hd, int kt) -> short8 {
    return *(const short8*)((const short*)Wc + (o0 + lane15) * 512 + hd * 64 + kt * 32 + quad * 8);
  };
  // A-frag from g [64][74] bf16 (rows 4B- but not 16B-aligned -> 4x b32)
  auto ldA_g = [&](int mt, int kt) -> short8 {
    int tt = mt * 16 + lane15;
    int widx = tt * 37 + kt * 16 + quad * 4;
    const unsigned int* q = (const unsigned int*)smg + widx;
    union { unsigned int u[4]; short8 v; } f;
    f.u[0] = q[0]; f.u[1] = q[1]; f.u[2] = q[2]; f.u[3] = q[3];
    return f.v;
  };

  long ubase; int ustride;
  if (DIR == 0) { ubase = (long)s * 16384; ustride = 256; }
  else { ubase = (long)(s >> 6) * 1048576 + (long)(s & 63) * 256; ustride = 16384; }

  // ---- stage u -> bf16 LDS [t][c], paired packing ----
  for (int i = tid; i < 8192; i += NTH) {
    int tt = i >> 7, c2 = (i & 127) * 2;
    float a0 = x[ubase + (long)tt * ustride + c2];
    float a1 = x[ubase + (long)tt * ustride + c2 + 1];
    unsigned int pw = (unsigned int)(unsigned short)f2bs(a0)
                    | ((unsigned int)(unsigned short)f2bs(a1) << 16);
    ((unsigned int*)smU)[tt * 132 + (i & 127)] = pw;
  }
  if (tid < 64) smSSQ[tid] = 0.f;
  __syncthreads();

  // ---- MFMA: B/C/dt projection (in_w rows 1024..1167, 9 n-tiles) ----
  for (int jt = w; jt < 9; jt += 8) {
    floatx4 acc0 = (floatx4)0.f, acc1 = (floatx4)0.f, acc2 = (floatx4)0.f, acc3 = (floatx4)0.f;
#pragma unroll
    for (int kt = 0; kt < 8; ++kt) {
      short8 b = ldB_w(1024 + jt * 16, kt);
      acc0 = MF(ldA_u(0, kt), b, acc0);
      acc1 = MF(ldA_u(1, kt), b, acc1);
      acc2 = MF(ldA_u(2, kt), b, acc2);
      acc3 = MF(ldA_u(3, kt), b, acc3);
    }
    int q = jt * 16 + lane15;
    float* dst = raw + q * 68 + quad * 4;
#pragma unroll
    for (int r = 0; r < 4; ++r) { dst[r] = acc0[r]; dst[16 + r] = acc1[r];
                                  dst[32 + r] = acc2[r]; dst[48 + r] = acc3[r]; }
  }
  __syncthreads();

  // ---- conv+silu on B/C -> smBC (bf16); dt softplus + cum scan ----
  {
#pragma unroll
    for (int ii = 0; ii < 16; ++ii) {
      int q = w + ii * 8;
      int ch = 512 + q;
      const float* base = raw + q * 68 + t;
      float v3 = base[0];
      float v2 = (t >= 1) ? base[-1] : 0.f;
      float v1 = (t >= 2) ? base[-2] : 0.f;
      float v0 = (t >= 3) ? base[-3] : 0.f;
      const float4 cw = *(const float4*)(conv_w + ch * 4);
      float v = cw.x*v0 + cw.y*v1 + cw.z*v2 + cw.w*v3 + conv_b[ch];
      smBC[q * 64 + t] = f2bs(silu_f(v));
    }
    float dtv = softplus_f(raw[(128 + w) * 68 + t] + dt_bias[w]);
    smDT[w * 64 + t] = dtv;
    float cum = -__expf(A_log[w]) * dtv;
#pragma unroll
    for (int off = 1; off < 64; off <<= 1) {
      float y = __shfl_up(cum, off, 64);
      if (t >= off) cum += y;
    }
    smCUM[w * 64 + t] = cum;
  }
  __syncthreads();

  // ---- G[s][t] = sum_n C[t][n]*B[s][n] (VALU) ----
  {
    float acc[8];
#pragma unroll
    for (int ii = 0; ii < 8; ++ii) acc[ii] = 0.f;
    for (int n = 0; n < 64; ++n) {
      float cv = bs2f(smBC[(64 + n) * 64 + t]);
#pragma unroll
      for (int ii = 0; ii < 8; ++ii)
        acc[ii] += cv * bs2f(smBC[n * 64 + (w + ii * 8)]);
    }
#pragma unroll
    for (int ii = 0; ii < 8; ++ii) smG[(w + ii * 8) * 64 + t] = acc[ii];
  }
  // (M-step reads smG only after the post-xz sync below)

  floatx4 accO[4][2];
#pragma unroll
  for (int m = 0; m < 4; ++m) { accO[m][0] = (floatx4)0.f; accO[m][1] = (floatx4)0.f; }

  for (int hd = 0; hd < 8; ++hd) {
    // MFMA: x,z head projection. wave w = n-tile w (w<4: z rows hd*64.., w>=4: x rows 512+hd*64..)
    {
      int row0 = (w < 4) ? (hd * 64 + w * 16) : (512 + hd * 64 + (w - 4) * 16);
      float* dstbase = (w < 4) ? (zh + (w * 16 + lane15) * 68)
                               : (xh + ((w - 4) * 16 + lane15) * 68);
      floatx4 acc0 = (floatx4)0.f, acc1 = (floatx4)0.f, acc2 = (floatx4)0.f, acc3 = (floatx4)0.f;
#pragma unroll
      for (int kt = 0; kt < 8; ++kt) {
        short8 b = ldB_w(row0, kt);
        acc0 = MF(ldA_u(0, kt), b, acc0);
        acc1 = MF(ldA_u(1, kt), b, acc1);
        acc2 = MF(ldA_u(2, kt), b, acc2);
        acc3 = MF(ldA_u(3, kt), b, acc3);
      }
      float* dst = dstbase + quad * 4;
#pragma unroll
      for (int r = 0; r < 4; ++r) { dst[r] = acc0[r]; dst[16 + r] = acc1[r];
                                    dst[32 + r] = acc2[r]; dst[48 + r] = acc3[r]; }
    }
    __syncthreads();

    // conv-read taps (regs) + M-matrix build
    float r0[8], r1[8], r2[8], r3[8];
#pragma unroll
    for (int ii = 0; ii < 8; ++ii) {
      int p = w + ii * 8;
      const float* base = xh + p * 68 + t;
      r3[ii] = base[0];
      r2[ii] = (t >= 1) ? base[-1] : 0.f;
      r1[ii] = (t >= 2) ? base[-2] : 0.f;
      r0[ii] = (t >= 3) ? base[-3] : 0.f;
    }
    {
      const float* cumh = smCUM + hd * 64;
      const float* dth  = smDT + hd * 64;
      for (int idx = tid; idx < 4096; idx += NTH) {
        int ss = idx >> 6, tt = idx & 63;
        float m = 0.f;
        if (tt >= ss) m = __expf(cumh[tt] - cumh[ss]) * dth[ss] * smG[idx];
        smM[idx] = m;
      }
    }
    __syncthreads();
#pragma unroll
    for (int ii = 0; ii < 8; ++ii) {
      int p = w + ii * 8, ch = hd * 64 + p;
      const float4 cw = *(const float4*)(conv_w + ch * 4);
      float v = cw.x*r0[ii] + cw.y*r1[ii] + cw.z*r2[ii] + cw.w*r3[ii] + conv_b[ch];
      xh[p * 68 + t] = silu_f(v);
    }
    __syncthreads();

    // D4: Y = M @ X (VALU), D-term, silu(z) gating, ssq, g -> [t][j] bf16
    {
      float acc[8];
#pragma unroll
      for (int ii = 0; ii < 8; ++ii) acc[ii] = 0.f;
      for (int s4 = 0; s4 < 64; s4 += 4) {
        float m0 = smM[(s4 + 0) * 64 + t];
        float m1 = smM[(s4 + 1) * 64 + t];
        float m2 = smM[(s4 + 2) * 64 + t];
        float m3 = smM[(s4 + 3) * 64 + t];
#pragma unroll
        for (int ii = 0; ii < 8; ++ii) {
          const float4 xv = *(const float4*)(xh + (w + ii * 8) * 68 + s4);
          acc[ii] += m0*xv.x + m1*xv.y + m2*xv.z + m3*xv.w;
        }
      }
      float Dh = Dvec[hd];
      float part = 0.f;
#pragma unroll
      for (int ii = 0; ii < 8; ++ii) {
        int p = w + ii * 8;
        float yv = acc[ii] + Dh * xh[p * 68 + t];
        float zv = zh[p * 68 + t];
        float g = yv * silu_f(zv);
        part += g * g;
        smg[t * 74 + p] = f2bs(g);
      }
      atomicAdd(&smSSQ[t], part);
    }
    __syncthreads();

    // D5: accO[m][n] += g-tile x Wc-tile (MFMA), K=64 per head
#pragma unroll
    for (int kt = 0; kt < 2; ++kt) {
      short8 b0 = ldB_wc(w * 16, hd, kt);
      short8 b1 = ldB_wc((w + 8) * 16, hd, kt);
#pragma unroll
      for (int m = 0; m < 4; ++m) {
        short8 a = ldA_g(m, kt);
        accO[m][0] = MF(a, b0, accO[m][0]);
        accO[m][1] = MF(a, b1, accO[m][1]);
      }
    }
    __syncthreads();
  }

  // ---- epilogue: RMS scale, direct C-layout global writes ----
  if (tid < 64) smRMS[tid] = rsqrtf(smSSQ[tid] * (1.f / 512.f) + 1e-5f);
  __syncthreads();
#pragma unroll
  for (int m = 0; m < 4; ++m) {
#pragma unroll
    for (int n = 0; n < 2; ++n) {
      int o = (w + n * 8) * 16 + lane15;
#pragma unroll
      for (int r = 0; r < 4; ++r) {
        int tt = m * 16 + quad * 4 + r;
        float val = accO[m][n][r] * smRMS[tt];
        long rowg = (DIR == 0) ? ((long)s * 64 + tt)
                               : ((long)(s >> 6) * 4096 + (long)tt * 64 + (s & 63));
        long gi = rowg * 256 + o;
        if (DIR == 0) out[gi] = fc_b[o] + val;
        else          out[gi] += val;
      }
    }
  }
}

extern "C" void kernel_launch(void* const* d_in, const int* in_sizes, int n_in,
                              void* d_out, int out_size, void* d_ws, size_t ws_size,
                              hipStream_t stream) {
  const float* x          = (const float*)d_in[0];
  const float* mh_in_w    = (const float*)d_in[1];
  const float* mh_conv_w  = (const float*)d_in[2];
  const float* mh_conv_b  = (const float*)d_in[3];
  const float* mh_dt_bias = (const float*)d_in[4];
  const float* mh_A_log   = (const float*)d_in[5];
  const float* mh_D       = (const float*)d_in[6];
  const float* mh_norm_w  = (const float*)d_in[7];
  const float* mh_out_w   = (const float*)d_in[8];
  const float* mv_in_w    = (const float*)d_in[9];
  const float* mv_conv_w  = (const float*)d_in[10];
  const float* mv_conv_b  = (const float*)d_in[11];
  const float* mv_dt_bias = (const float*)d_in[12];
  const float* mv_A_log   = (const float*)d_in[13];
  const float* mv_D       = (const float*)d_in[14];
  const float* mv_norm_w  = (const float*)d_in[15];
  const float* mv_out_w   = (const float*)d_in[16];
  const float* fc_w       = (const float*)d_in[17];
  const float* fc_b       = (const float*)d_in[18];
  float* out = (float*)d_out;

  __hip_bfloat16* Wcb  = (__hip_bfloat16*)d_ws;                       // 2*131072 bf16
  __hip_bfloat16* inwb = (__hip_bfloat16*)((char*)d_ws + 524288);     // 2*1168*256 bf16

  setup_wc<<<1024, 256, 0, stream>>>(fc_w, mh_out_w, mh_norm_w, mv_out_w, mv_norm_w, Wcb);
  cast_inw<<<2336, 256, 0, stream>>>(mh_in_w, mv_in_w, inwb);
  mamba_dir_kernel<0><<<512, NTH, 0, stream>>>(x, inwb, mh_conv_w, mh_conv_b,
      mh_dt_bias, mh_A_log, mh_D, Wcb, fc_b, out);
  mamba_dir_kernel<1><<<512, NTH, 0, stream>>>(x, inwb + 299008, mv_conv_w, mv_conv_b,
      mv_dt_bias, mv_A_log, mv_D, Wcb + 131072, fc_b, out);
}

// Round 4
// 439.460 us; speedup vs baseline: 6.4054x; 1.2615x over previous
//
#include <hip/hip_runtime.h>
#include <hip/hip_bf16.h>

// MAMBA2_2D fused kernel, round 4: ALL matmul-shaped work on bf16 MFMA:
// in-proj (B/C/dt), per-head x/z proj, G = C B^T, Y = M X, folded out-proj.
// VALU keeps: convs, M decay-mask build, gating, RMS. Output float32.

#define NTH 512

typedef __attribute__((ext_vector_type(8))) short short8;
typedef __attribute__((ext_vector_type(4))) float floatx4;

__device__ __forceinline__ float silu_f(float v){ return v / (1.f + __expf(-v)); }
__device__ __forceinline__ float softplus_f(float v){
  return fmaxf(v, 0.f) + log1pf(__expf(-fabsf(v)));
}
__device__ __forceinline__ short f2bs(float v){
  __hip_bfloat16 h = __float2bfloat16(v);
  return *reinterpret_cast<short*>(&h);
}
__device__ __forceinline__ float bs2f(short s){
  __hip_bfloat16 h = *reinterpret_cast<__hip_bfloat16*>(&s);
  return __bfloat162float(h);
}

__global__ void setup_wc(const float* __restrict__ fc_w,
                         const float* __restrict__ how, const float* __restrict__ hnw,
                         const float* __restrict__ vow, const float* __restrict__ vnw,
                         __hip_bfloat16* __restrict__ Wc)
{
  int id = blockIdx.x * blockDim.x + threadIdx.x;
  if (id >= 262144) return;
  int dir = id >> 17;
  int r = id & 131071;
  int o = r >> 9, j = r & 511;
  const float* ow = dir ? vow : how;
  const float* nw = dir ? vnw : hnw;
  int off = dir ? 0 : 512;
  const float* fr = fc_w + o * 1024 + off;
  float acc = 0.f;
  for (int k = 0; k < 256; ++k) acc += (fr[k] + fr[256 + k]) * ow[k * 512 + j];
  Wc[id] = __float2bfloat16(nw[j] * acc);
}

__global__ void cast_inw(const float* __restrict__ hw, const float* __restrict__ vw,
                         __hip_bfloat16* __restrict__ dst)
{
  int id = blockIdx.x * blockDim.x + threadIdx.x;   // 2*1168*256
  if (id >= 598016) return;
  int dir = id / 299008;
  int r = id % 299008;
  int row = r >> 8;
  const float* src = dir ? vw : hw;
  float v = (row < 1160) ? src[r] : 0.f;
  dst[id] = __float2bfloat16(v);
}

// LDS float offsets
#define OFF_RAW   8448   // fp32 [144][68] (BCdt proj out) U {xraw [64][68]@8448, zh [64][68]@12800}
#define OFF_XRAW  8448
#define OFF_ZH    12800
#define OFF_B     18240  // bf16 [64][72]  B[s][n]   U  smM bf16 [64][72]
#define OFF_M     18240
#define OFF_C     20544  // bf16 [64][72]  C[t][n]   U  smX bf16 [64][72]
#define OFF_X     20544
#define OFF_G     22848  // fp32 [64][68]  G[t][s]
#define OFF_GB    27200  // bf16 [64][72]  g[t][j]
#define OFF_DT    29504  // fp32 [8][64]
#define OFF_CUM   30016  // fp32 [8][64]
#define OFF_SSQ   30528  // fp32 [64]
#define OFF_RMS   30592  // fp32 [64]
#define SM_TOT    30656  // 122624 bytes

template<int DIR>
__global__ __launch_bounds__(NTH)
void mamba_dir_kernel(const float* __restrict__ x,
                      const __hip_bfloat16* __restrict__ inw_bf,  // [1168][256]
                      const float* __restrict__ conv_w,
                      const float* __restrict__ conv_b,
                      const float* __restrict__ dt_bias,
                      const float* __restrict__ A_log,
                      const float* __restrict__ Dvec,
                      const __hip_bfloat16* __restrict__ Wc,      // [256][512]
                      const float* __restrict__ fc_b,
                      float* __restrict__ out)
{
  __shared__ float sm[SM_TOT];
  short* smU  = (short*)sm;               // bf16 [64][264]
  float* raw  = sm + OFF_RAW;
  float* xraw = sm + OFF_XRAW;
  float* zh   = sm + OFF_ZH;
  short* smB  = (short*)(sm + OFF_B);
  short* smM  = (short*)(sm + OFF_M);
  short* smC  = (short*)(sm + OFF_C);
  short* smX  = (short*)(sm + OFF_X);
  float* smG  = sm + OFF_G;
  short* smg  = (short*)(sm + OFF_GB);
  float* smDT  = sm + OFF_DT;
  float* smCUM = sm + OFF_CUM;
  float* smSSQ = sm + OFF_SSQ;
  float* smRMS = sm + OFF_RMS;

  const int tid = threadIdx.x;
  const int t = tid & 63;
  const int w = tid >> 6;
  const int lane15 = tid & 15;
  const int quad = (tid & 63) >> 4;
  const int s = blockIdx.x;

  auto MF = [](short8 a, short8 b, floatx4 c) -> floatx4 {
    return __builtin_amdgcn_mfma_f32_16x16x32_bf16(a, b, c, 0, 0, 0);
  };
  auto ldA_u = [&](int mt, int kt) -> short8 {
    return *(const short8*)(smU + (mt * 16 + lane15) * 264 + kt * 32 + quad * 8);
  };
  auto ldB_w = [&](int row0, int kt) -> short8 {
    return *(const short8*)((const short*)inw_bf + (row0 + lane15) * 256 + kt * 32 + quad * 8);
  };
  auto ldB_wc = [&](int o0, int hd, int kt) -> short8 {
    return *(const short8*)((const short*)Wc + (o0 + lane15) * 512 + hd * 64 + kt * 32 + quad * 8);
  };
  auto ld72 = [&](const short* base, int row, int kt) -> short8 {
    return *(const short8*)(base + row * 72 + kt * 32 + quad * 8);
  };
  // one n-tile (16 output channels at weight row0) x 64 timesteps, K=256
  auto proj_tile = [&](int row0, float* dst /* base + lane15*68 + quad*4 */) {
    floatx4 a0 = (floatx4)0.f, a1 = (floatx4)0.f, a2 = (floatx4)0.f, a3 = (floatx4)0.f;
#pragma unroll
    for (int kt = 0; kt < 8; ++kt) {
      short8 b = ldB_w(row0, kt);
      a0 = MF(ldA_u(0, kt), b, a0);
      a1 = MF(ldA_u(1, kt), b, a1);
      a2 = MF(ldA_u(2, kt), b, a2);
      a3 = MF(ldA_u(3, kt), b, a3);
    }
#pragma unroll
    for (int r = 0; r < 4; ++r) { dst[r] = a0[r]; dst[16 + r] = a1[r];
                                  dst[32 + r] = a2[r]; dst[48 + r] = a3[r]; }
  };

  long ubase; int ustride;
  if (DIR == 0) { ubase = (long)s * 16384; ustride = 256; }
  else { ubase = (long)(s >> 6) * 1048576 + (long)(s & 63) * 256; ustride = 16384; }

  // ---- stage u -> bf16 [t][264] ----
  for (int i = tid; i < 8192; i += NTH) {
    int tt = i >> 7, c2 = (i & 127) * 2;
    float a0 = x[ubase + (long)tt * ustride + c2];
    float a1 = x[ubase + (long)tt * ustride + c2 + 1];
    unsigned int pw = (unsigned int)(unsigned short)f2bs(a0)
                    | ((unsigned int)(unsigned short)f2bs(a1) << 16);
    ((unsigned int*)smU)[tt * 132 + (i & 127)] = pw;
  }
  if (tid < 64) smSSQ[tid] = 0.f;
  __syncthreads();

  // ---- BCdt projection (rows 1024..1167, 9 n-tiles) ----
  for (int jt = w; jt < 9; jt += 8)
    proj_tile(1024 + jt * 16, raw + (jt * 16 + lane15) * 68 + quad * 4);
  __syncthreads();

  // ---- conv+silu on B/C -> smB [s][n], smC [t][n] (bf16); dt softplus + cum ----
  {
#pragma unroll
    for (int ii = 0; ii < 16; ++ii) {
      int q = w + ii * 8;            // 0..127
      int ch = 512 + q;
      const float* base = raw + q * 68 + t;
      float v3 = base[0];
      float v2 = (t >= 1) ? base[-1] : 0.f;
      float v1 = (t >= 2) ? base[-2] : 0.f;
      float v0 = (t >= 3) ? base[-3] : 0.f;
      const float4 cw = *(const float4*)(conv_w + ch * 4);
      float v = cw.x*v0 + cw.y*v1 + cw.z*v2 + cw.w*v3 + conv_b[ch];
      short sv = f2bs(silu_f(v));
      if (q < 64) smB[t * 72 + q] = sv;
      else        smC[t * 72 + (q - 64)] = sv;
    }
    float dtv = softplus_f(raw[(128 + w) * 68 + t] + dt_bias[w]);
    smDT[w * 64 + t] = dtv;
    float cum = -__expf(A_log[w]) * dtv;
#pragma unroll
    for (int off = 1; off < 64; off <<= 1) {
      float y = __shfl_up(cum, off, 64);
      if (t >= off) cum += y;
    }
    smCUM[w * 64 + t] = cum;
  }
  __syncthreads();

  // ---- G = C B^T via MFMA: G[t][s], wave w -> m-tile w>>1, n-tiles (w&1)*2+{0,1} ----
  {
    int mt = w >> 1, nt0 = (w & 1) * 2;
    floatx4 g0 = (floatx4)0.f, g1 = (floatx4)0.f;
#pragma unroll
    for (int kt = 0; kt < 2; ++kt) {
      short8 a  = ld72(smC, mt * 16 + lane15, kt);
      short8 b0 = ld72(smB, nt0 * 16 + lane15, kt);
      short8 b1 = ld72(smB, (nt0 + 1) * 16 + lane15, kt);
      g0 = MF(a, b0, g0); g1 = MF(a, b1, g1);
    }
#pragma unroll
    for (int r = 0; r < 4; ++r) {
      int tt = mt * 16 + quad * 4 + r;
      smG[tt * 68 + nt0 * 16 + lane15]       = g0[r];
      smG[tt * 68 + (nt0 + 1) * 16 + lane15] = g1[r];
    }
  }
  // smG consumed only after the next barrier (inside head loop)

  floatx4 accO[4][2];
#pragma unroll
  for (int m = 0; m < 4; ++m) { accO[m][0] = (floatx4)0.f; accO[m][1] = (floatx4)0.f; }

  for (int hd = 0; hd < 8; ++hd) {
    // x/z head projection: waves 0..3 -> z (rows hd*64..), 4..7 -> x (rows 512+hd*64..)
    {
      int row0 = (w < 4) ? (hd * 64 + w * 16) : (512 + hd * 64 + (w - 4) * 16);
      float* dst = ((w < 4) ? (zh + (w * 16 + lane15) * 68)
                            : (xraw + ((w - 4) * 16 + lane15) * 68)) + quad * 4;
      proj_tile(row0, dst);
    }
    __syncthreads();

    // conv+silu x -> smX bf16 [p][s];  M build -> smM bf16 [t][s]
    {
#pragma unroll
      for (int ii = 0; ii < 8; ++ii) {
        int p = w + ii * 8, ch = hd * 64 + p;
        const float* base = xraw + p * 68 + t;
        float v3 = base[0];
        float v2 = (t >= 1) ? base[-1] : 0.f;
        float v1 = (t >= 2) ? base[-2] : 0.f;
        float v0 = (t >= 3) ? base[-3] : 0.f;
        const float4 cw = *(const float4*)(conv_w + ch * 4);
        float v = cw.x*v0 + cw.y*v1 + cw.z*v2 + cw.w*v3 + conv_b[ch];
        smX[p * 72 + t] = f2bs(silu_f(v));
      }
      const float* cumh = smCUM + hd * 64;
      const float* dth  = smDT + hd * 64;
#pragma unroll
      for (int k = 0; k < 8; ++k) {
        int tt = k * 8 + w, ss = t;
        float m = 0.f;
        if (tt >= ss) m = __expf(cumh[tt] - cumh[ss]) * dth[ss] * smG[tt * 68 + ss];
        smM[tt * 72 + ss] = f2bs(m);
      }
    }
    __syncthreads();

    // Y = M X via MFMA + D-term + silu(z) gating -> smg bf16 [t][j]
    {
      int mt = w >> 1, nt0 = (w & 1) * 2;
      floatx4 y0 = (floatx4)0.f, y1 = (floatx4)0.f;
#pragma unroll
      for (int kt = 0; kt < 2; ++kt) {
        short8 a  = ld72(smM, mt * 16 + lane15, kt);
        short8 b0 = ld72(smX, nt0 * 16 + lane15, kt);
        short8 b1 = ld72(smX, (nt0 + 1) * 16 + lane15, kt);
        y0 = MF(a, b0, y0); y1 = MF(a, b1, y1);
      }
      float Dh = Dvec[hd];
#pragma unroll
      for (int j = 0; j < 2; ++j) {
        floatx4 yy = j ? y1 : y0;
        int p = (nt0 + j) * 16 + lane15;
#pragma unroll
        for (int r = 0; r < 4; ++r) {
          int tr = mt * 16 + quad * 4 + r;
          float xv = bs2f(smX[p * 72 + tr]);
          float zv = zh[p * 68 + tr];
          float g = (yy[r] + Dh * xv) * silu_f(zv);
          smg[tr * 72 + p] = f2bs(g);
        }
      }
    }
    __syncthreads();

    // ssq readback + D5 out-proj MFMA
    {
      short8 gv = *(const short8*)(smg + t * 72 + w * 8);
      float part = 0.f;
#pragma unroll
      for (int j = 0; j < 8; ++j) { float g = bs2f(gv[j]); part += g * g; }
      atomicAdd(&smSSQ[t], part);
    }
#pragma unroll
    for (int kt = 0; kt < 2; ++kt) {
      short8 b0 = ldB_wc(w * 16, hd, kt);
      short8 b1 = ldB_wc((w + 8) * 16, hd, kt);
#pragma unroll
      for (int m = 0; m < 4; ++m) {
        short8 a = ld72(smg, m * 16 + lane15, kt);
        accO[m][0] = MF(a, b0, accO[m][0]);
        accO[m][1] = MF(a, b1, accO[m][1]);
      }
    }
    // next iter's proj writes zh/xraw (read in gating, pre-barrier) — safe;
    // next writes to smg happen 2 barriers ahead — safe.
  }

  __syncthreads();
  if (tid < 64) smRMS[tid] = rsqrtf(smSSQ[tid] * (1.f / 512.f) + 1e-5f);
  __syncthreads();

  // ---- epilogue: RMS scale, direct C-layout global writes ----
#pragma unroll
  for (int m = 0; m < 4; ++m) {
#pragma unroll
    for (int n = 0; n < 2; ++n) {
      int o = (w + n * 8) * 16 + lane15;
#pragma unroll
      for (int r = 0; r < 4; ++r) {
        int tt = m * 16 + quad * 4 + r;
        float val = accO[m][n][r] * smRMS[tt];
        long rowg = (DIR == 0) ? ((long)s * 64 + tt)
                               : ((long)(s >> 6) * 4096 + (long)tt * 64 + (s & 63));
        long gi = rowg * 256 + o;
        if (DIR == 0) out[gi] = fc_b[o] + val;
        else          out[gi] += val;
      }
    }
  }
}

extern "C" void kernel_launch(void* const* d_in, const int* in_sizes, int n_in,
                              void* d_out, int out_size, void* d_ws, size_t ws_size,
                              hipStream_t stream) {
  const float* x          = (const float*)d_in[0];
  const float* mh_in_w    = (const float*)d_in[1];
  const float* mh_conv_w  = (const float*)d_in[2];
  const float* mh_conv_b  = (const float*)d_in[3];
  const float* mh_dt_bias = (const float*)d_in[4];
  const float* mh_A_log   = (const float*)d_in[5];
  const float* mh_D       = (const float*)d_in[6];
  const float* mh_norm_w  = (const float*)d_in[7];
  const float* mh_out_w   = (const float*)d_in[8];
  const float* mv_in_w    = (const float*)d_in[9];
  const float* mv_conv_w  = (const float*)d_in[10];
  const float* mv_conv_b  = (const float*)d_in[11];
  const float* mv_dt_bias = (const float*)d_in[12];
  const float* mv_A_log   = (const float*)d_in[13];
  const float* mv_D       = (const float*)d_in[14];
  const float* mv_norm_w  = (const float*)d_in[15];
  const float* mv_out_w   = (const float*)d_in[16];
  const float* fc_w       = (const float*)d_in[17];
  const float* fc_b       = (const float*)d_in[18];
  float* out = (float*)d_out;

  __hip_bfloat16* Wcb  = (__hip_bfloat16*)d_ws;                       // 2*131072 bf16
  __hip_bfloat16* inwb = (__hip_bfloat16*)((char*)d_ws + 524288);     // 2*1168*256 bf16

  setup_wc<<<1024, 256, 0, stream>>>(fc_w, mh_out_w, mh_norm_w, mv_out_w, mv_norm_w, Wcb);
  cast_inw<<<2336, 256, 0, stream>>>(mh_in_w, mv_in_w, inwb);
  mamba_dir_kernel<0><<<512, NTH, 0, stream>>>(x, inwb, mh_conv_w, mh_conv_b,
      mh_dt_bias, mh_A_log, mh_D, Wcb, fc_b, out);
  mamba_dir_kernel<1><<<512, NTH, 0, stream>>>(x, inwb + 299008, mv_conv_w, mv_conv_b,
      mv_dt_bias, mv_A_log, mv_D, Wcb + 131072, fc_b, out);
}

// Round 5
// 364.809 us; speedup vs baseline: 7.7161x; 1.2046x over previous
//
#include <hip/hip_runtime.h>
#include <hip/hip_bf16.h>

// MAMBA2_2D fused kernel, round 5: LDS squeezed 122.9 -> 79.4 KB so two
// 512-thread blocks co-reside per CU (4 waves/SIMD) to hide barrier drains.
// Proj outputs / G / dt stored bf16; g reuses M buffer (+1 barrier/head);
// SSQ/RMS live in smU pad columns. All matmul work on bf16 MFMA as round 4.

#define NTH 512

typedef __attribute__((ext_vector_type(8))) short short8;
typedef __attribute__((ext_vector_type(4))) float floatx4;

__device__ __forceinline__ float silu_f(float v){ return v / (1.f + __expf(-v)); }
__device__ __forceinline__ float softplus_f(float v){
  return fmaxf(v, 0.f) + log1pf(__expf(-fabsf(v)));
}
__device__ __forceinline__ short f2bs(float v){
  __hip_bfloat16 h = __float2bfloat16(v);
  return *reinterpret_cast<short*>(&h);
}
__device__ __forceinline__ float bs2f(short s){
  __hip_bfloat16 h = *reinterpret_cast<__hip_bfloat16*>(&s);
  return __bfloat162float(h);
}

// merged setup: blocks 0..1023 build Wc (folded fc+out_w+norm_w, bf16);
// blocks 1024..3359 cast in_w fp32 -> bf16 [1168][256] (rows 1160+ zero).
__global__ void setup_weights(const float* __restrict__ fc_w,
                              const float* __restrict__ how, const float* __restrict__ hnw,
                              const float* __restrict__ vow, const float* __restrict__ vnw,
                              const float* __restrict__ hw, const float* __restrict__ vw,
                              __hip_bfloat16* __restrict__ Wc,
                              __hip_bfloat16* __restrict__ inw)
{
  int b = blockIdx.x;
  if (b < 1024) {
    int id = b * 256 + threadIdx.x;           // 262144
    int dir = id >> 17;
    int r = id & 131071;
    int o = r >> 9, j = r & 511;
    const float* ow = dir ? vow : how;
    const float* nw = dir ? vnw : hnw;
    int off = dir ? 0 : 512;
    const float* fr = fc_w + o * 1024 + off;
    float acc = 0.f;
    for (int k = 0; k < 256; ++k) acc += (fr[k] + fr[256 + k]) * ow[k * 512 + j];
    Wc[id] = __float2bfloat16(nw[j] * acc);
  } else {
    int id = (b - 1024) * 256 + threadIdx.x;  // 598016 = 2*1168*256
    int dir = id / 299008;
    int r = id % 299008;
    int row = r >> 8;
    const float* src = dir ? vw : hw;
    float v = (row < 1160) ? src[r] : 0.f;
    inw[id] = __float2bfloat16(v);
  }
}

// LDS short-offsets (total 40648 shorts = 81296 B)
#define OFS_U    0       // bf16 [64][264] staged u; pad cols 256..259 hold SSQ/RMS fp32
#define OFS_R1   16896   // bf16 [136][65]: phase A raw BCdt [ch][t]; head loop z rows 0..63, x rows 64..127
#define OFS_BX0  25736   // bf16 [64][72]: B[s][n] -> M[t][s] -> g[t][j]
#define OFS_BX1  30344   // bf16 [64][72]: C[t][n] -> X[p][s]
#define OFS_G    34952   // bf16 [64][65]: G[t][s]
#define OFS_CUM  39112   // fp32 [8][64] (byte 78224)
#define OFS_DT   40136   // bf16 [8][64]
#define SM_SHORTS 40648

template<int DIR>
__global__ __launch_bounds__(NTH, 4)
void mamba_dir_kernel(const float* __restrict__ x,
                      const __hip_bfloat16* __restrict__ inw_bf,  // [1168][256]
                      const float* __restrict__ conv_w,
                      const float* __restrict__ conv_b,
                      const float* __restrict__ dt_bias,
                      const float* __restrict__ A_log,
                      const float* __restrict__ Dvec,
                      const __hip_bfloat16* __restrict__ Wc,      // [256][512]
                      const float* __restrict__ fc_b,
                      float* __restrict__ out)
{
  __shared__ short sm[SM_SHORTS];
  short* smU  = sm + OFS_U;
  short* smR1 = sm + OFS_R1;
  short* smB  = sm + OFS_BX0;   // aliases smM, smg
  short* smM  = sm + OFS_BX0;
  short* smg  = sm + OFS_BX0;
  short* smC  = sm + OFS_BX1;   // aliases smX
  short* smX  = sm + OFS_BX1;
  short* smG  = sm + OFS_G;
  float* smCUM = (float*)(sm + OFS_CUM);
  short* smDT  = sm + OFS_DT;
  float* smF   = (float*)sm;    // SSQ at [t*132+128], RMS at [t*132+129] (smU pad)

  const int tid = threadIdx.x;
  const int t = tid & 63;
  const int w = tid >> 6;
  const int lane15 = tid & 15;
  const int quad = (tid & 63) >> 4;
  const int s = blockIdx.x;

  auto MF = [](short8 a, short8 b, floatx4 c) -> floatx4 {
    return __builtin_amdgcn_mfma_f32_16x16x32_bf16(a, b, c, 0, 0, 0);
  };
  auto ldA_u = [&](int mt, int kt) -> short8 {
    return *(const short8*)(smU + (mt * 16 + lane15) * 264 + kt * 32 + quad * 8);
  };
  auto ldB_w = [&](int row0, int kt) -> short8 {
    return *(const short8*)((const short*)inw_bf + (row0 + lane15) * 256 + kt * 32 + quad * 8);
  };
  auto ldB_wc = [&](int o0, int hd, int kt) -> short8 {
    return *(const short8*)((const short*)Wc + (o0 + lane15) * 512 + hd * 64 + kt * 32 + quad * 8);
  };
  auto ld72 = [&](const short* base, int row, int kt) -> short8 {
    return *(const short8*)(base + row * 72 + kt * 32 + quad * 8);
  };
  // one n-tile (16 out-channels at weight row0) x all 64 t, K=256; bf16 C-layout store
  // dst = smR1 + q*65 + quad*4 (q = channel row); wr=false masks pad channels
  auto proj_tile = [&](int row0, short* dst, bool wr) {
    floatx4 a0 = (floatx4)0.f, a1 = (floatx4)0.f, a2 = (floatx4)0.f, a3 = (floatx4)0.f;
#pragma unroll
    for (int kt = 0; kt < 8; ++kt) {
      short8 b = ldB_w(row0, kt);
      a0 = MF(ldA_u(0, kt), b, a0);
      a1 = MF(ldA_u(1, kt), b, a1);
      a2 = MF(ldA_u(2, kt), b, a2);
      a3 = MF(ldA_u(3, kt), b, a3);
    }
    if (wr) {
#pragma unroll
      for (int r = 0; r < 4; ++r) {
        dst[r]      = f2bs(a0[r]); dst[16 + r] = f2bs(a1[r]);
        dst[32 + r] = f2bs(a2[r]); dst[48 + r] = f2bs(a3[r]);
      }
    }
  };

  long ubase; int ustride;
  if (DIR == 0) { ubase = (long)s * 16384; ustride = 256; }
  else { ubase = (long)(s >> 6) * 1048576 + (long)(s & 63) * 256; ustride = 16384; }

  // ---- stage u -> bf16 [t][264] (cols 0..255) ----
  for (int i = tid; i < 8192; i += NTH) {
    int tt = i >> 7, c2 = (i & 127) * 2;
    float a0 = x[ubase + (long)tt * ustride + c2];
    float a1 = x[ubase + (long)tt * ustride + c2 + 1];
    unsigned int pw = (unsigned int)(unsigned short)f2bs(a0)
                    | ((unsigned int)(unsigned short)f2bs(a1) << 16);
    ((unsigned int*)smU)[tt * 132 + (i & 127)] = pw;
  }
  if (tid < 64) smF[tid * 132 + 128] = 0.f;   // SSQ
  __syncthreads();

  // ---- BCdt projection (in_w rows 1024..1167, 9 n-tiles) -> smR1 bf16 [136][65] ----
  for (int jt = w; jt < 9; jt += 8) {
    int q = jt * 16 + lane15;
    proj_tile(1024 + jt * 16, smR1 + q * 65 + quad * 4, q < 136);
  }
  __syncthreads();

  // ---- conv+silu B/C -> smB [s][n] / smC [t][n]; dt softplus + cum scan ----
  {
#pragma unroll
    for (int ii = 0; ii < 16; ++ii) {
      int q = w + ii * 8;            // 0..127
      int ch = 512 + q;
      const short* base = smR1 + q * 65 + t;
      float v3 = bs2f(base[0]);
      float v2 = (t >= 1) ? bs2f(base[-1]) : 0.f;
      float v1 = (t >= 2) ? bs2f(base[-2]) : 0.f;
      float v0 = (t >= 3) ? bs2f(base[-3]) : 0.f;
      const float4 cw = *(const float4*)(conv_w + ch * 4);
      float v = cw.x*v0 + cw.y*v1 + cw.z*v2 + cw.w*v3 + conv_b[ch];
      short sv = f2bs(silu_f(v));
      if (q < 64) smB[t * 72 + q] = sv;
      else        smC[t * 72 + (q - 64)] = sv;
    }
    float dtv = softplus_f(bs2f(smR1[(128 + w) * 65 + t]) + dt_bias[w]);
    smDT[w * 64 + t] = f2bs(dtv);
    float cum = -__expf(A_log[w]) * dtv;
#pragma unroll
    for (int off = 1; off < 64; off <<= 1) {
      float y = __shfl_up(cum, off, 64);
      if (t >= off) cum += y;
    }
    smCUM[w * 64 + t] = cum;
  }
  __syncthreads();

  // ---- G = C B^T via MFMA -> smG bf16 [t][65-stride] ----
  {
    int mt = w >> 1, nt0 = (w & 1) * 2;
    floatx4 g0 = (floatx4)0.f, g1 = (floatx4)0.f;
#pragma unroll
    for (int kt = 0; kt < 2; ++kt) {
      short8 a  = ld72(smC, mt * 16 + lane15, kt);
      short8 b0 = ld72(smB, nt0 * 16 + lane15, kt);
      short8 b1 = ld72(smB, (nt0 + 1) * 16 + lane15, kt);
      g0 = MF(a, b0, g0); g1 = MF(a, b1, g1);
    }
#pragma unroll
    for (int r = 0; r < 4; ++r) {
      int tt = mt * 16 + quad * 4 + r;
      smG[tt * 65 + nt0 * 16 + lane15]       = f2bs(g0[r]);
      smG[tt * 65 + (nt0 + 1) * 16 + lane15] = f2bs(g1[r]);
    }
  }
  // smG consumed only after the post-P1 barrier of each head -> no sync needed here

  floatx4 accO[4][2];
#pragma unroll
  for (int m = 0; m < 4; ++m) { accO[m][0] = (floatx4)0.f; accO[m][1] = (floatx4)0.f; }

  for (int hd = 0; hd < 8; ++hd) {
    // P1: x/z head proj -> smR1 bf16 (z ch p -> row p; x ch p -> row 64+p)
    {
      int row0 = (w < 4) ? (hd * 64 + w * 16) : (512 + hd * 64 + (w - 4) * 16);
      int q = ((w < 4) ? w * 16 : 64 + (w - 4) * 16) + lane15;
      proj_tile(row0, smR1 + q * 65 + quad * 4, true);
    }
    __syncthreads();

    // P2: conv+silu x -> smX bf16 [p][s]; M build -> smM bf16 [t][s]
    {
#pragma unroll
      for (int ii = 0; ii < 8; ++ii) {
        int p = w + ii * 8, ch = hd * 64 + p;
        const short* base = smR1 + (64 + p) * 65 + t;
        float v3 = bs2f(base[0]);
        float v2 = (t >= 1) ? bs2f(base[-1]) : 0.f;
        float v1 = (t >= 2) ? bs2f(base[-2]) : 0.f;
        float v0 = (t >= 3) ? bs2f(base[-3]) : 0.f;
        const float4 cw = *(const float4*)(conv_w + ch * 4);
        float v = cw.x*v0 + cw.y*v1 + cw.z*v2 + cw.w*v3 + conv_b[ch];
        smX[p * 72 + t] = f2bs(silu_f(v));
      }
      const float* cumh = smCUM + hd * 64;
      const short* dth  = smDT + hd * 64;
#pragma unroll
      for (int k = 0; k < 8; ++k) {
        int tt = k * 8 + w, ss = t;
        float m = 0.f;
        if (tt >= ss)
          m = __expf(cumh[tt] - cumh[ss]) * bs2f(dth[ss]) * bs2f(smG[tt * 65 + ss]);
        smM[tt * 72 + ss] = f2bs(m);
      }
    }
    __syncthreads();

    // P3: Y = M X via MFMA (results stay in regs)
    int mt = w >> 1, nt0 = (w & 1) * 2;
    floatx4 y0 = (floatx4)0.f, y1 = (floatx4)0.f;
#pragma unroll
    for (int kt = 0; kt < 2; ++kt) {
      short8 a  = ld72(smM, mt * 16 + lane15, kt);
      short8 b0 = ld72(smX, nt0 * 16 + lane15, kt);
      short8 b1 = ld72(smX, (nt0 + 1) * 16 + lane15, kt);
      y0 = MF(a, b0, y0); y1 = MF(a, b1, y1);
    }
    __syncthreads();   // all M reads done before g overwrites the M buffer

    // P4: D-term + silu(z) gating -> g[t][j] into the M buffer
    {
      float Dh = Dvec[hd];
#pragma unroll
      for (int j = 0; j < 2; ++j) {
        floatx4 yy = j ? y1 : y0;
        int p = (nt0 + j) * 16 + lane15;
#pragma unroll
        for (int r = 0; r < 4; ++r) {
          int tr = mt * 16 + quad * 4 + r;
          float xv = bs2f(smX[p * 72 + tr]);
          float zv = bs2f(smR1[p * 65 + tr]);
          float g = (yy[r] + Dh * xv) * silu_f(zv);
          smg[tr * 72 + p] = f2bs(g);
        }
      }
    }
    __syncthreads();

    // P5: ssq + out-proj MFMA (g x Wc). Next P1 writes smR1 (disjoint) - safe.
    {
      short8 gv = *(const short8*)(smg + t * 72 + w * 8);
      float part = 0.f;
#pragma unroll
      for (int j = 0; j < 8; ++j) { float g = bs2f(gv[j]); part += g * g; }
      atomicAdd(&smF[t * 132 + 128], part);
    }
#pragma unroll
    for (int kt = 0; kt < 2; ++kt) {
      short8 b0 = ldB_wc(w * 16, hd, kt);
      short8 b1 = ldB_wc((w + 8) * 16, hd, kt);
#pragma unroll
      for (int m = 0; m < 4; ++m) {
        short8 a = ld72(smg, m * 16 + lane15, kt);
        accO[m][0] = MF(a, b0, accO[m][0]);
        accO[m][1] = MF(a, b1, accO[m][1]);
      }
    }
    // post-P1 barrier of next head guards P2's smM/smX writes vs this P5's reads
  }

  __syncthreads();
  if (tid < 64)
    smF[tid * 132 + 129] = rsqrtf(smF[tid * 132 + 128] * (1.f / 512.f) + 1e-5f);
  __syncthreads();

  // ---- epilogue: RMS scale, direct C-layout global writes ----
#pragma unroll
  for (int m = 0; m < 4; ++m) {
#pragma unroll
    for (int n = 0; n < 2; ++n) {
      int o = (w + n * 8) * 16 + lane15;
#pragma unroll
      for (int r = 0; r < 4; ++r) {
        int tt = m * 16 + quad * 4 + r;
        float val = accO[m][n][r] * smF[tt * 132 + 129];
        long rowg = (DIR == 0) ? ((long)s * 64 + tt)
                               : ((long)(s >> 6) * 4096 + (long)tt * 64 + (s & 63));
        long gi = rowg * 256 + o;
        if (DIR == 0) out[gi] = fc_b[o] + val;
        else          out[gi] += val;
      }
    }
  }
}

extern "C" void kernel_launch(void* const* d_in, const int* in_sizes, int n_in,
                              void* d_out, int out_size, void* d_ws, size_t ws_size,
                              hipStream_t stream) {
  const float* x          = (const float*)d_in[0];
  const float* mh_in_w    = (const float*)d_in[1];
  const float* mh_conv_w  = (const float*)d_in[2];
  const float* mh_conv_b  = (const float*)d_in[3];
  const float* mh_dt_bias = (const float*)d_in[4];
  const float* mh_A_log   = (const float*)d_in[5];
  const float* mh_D       = (const float*)d_in[6];
  const float* mh_norm_w  = (const float*)d_in[7];
  const float* mh_out_w   = (const float*)d_in[8];
  const float* mv_in_w    = (const float*)d_in[9];
  const float* mv_conv_w  = (const float*)d_in[10];
  const float* mv_conv_b  = (const float*)d_in[11];
  const float* mv_dt_bias = (const float*)d_in[12];
  const float* mv_A_log   = (const float*)d_in[13];
  const float* mv_D       = (const float*)d_in[14];
  const float* mv_norm_w  = (const float*)d_in[15];
  const float* mv_out_w   = (const float*)d_in[16];
  const float* fc_w       = (const float*)d_in[17];
  const float* fc_b       = (const float*)d_in[18];
  float* out = (float*)d_out;

  __hip_bfloat16* Wcb  = (__hip_bfloat16*)d_ws;                       // 2*131072 bf16
  __hip_bfloat16* inwb = (__hip_bfloat16*)((char*)d_ws + 524288);     // 2*1168*256 bf16

  setup_weights<<<3360, 256, 0, stream>>>(fc_w, mh_out_w, mh_norm_w, mv_out_w, mv_norm_w,
                                          mh_in_w, mv_in_w, Wcb, inwb);
  mamba_dir_kernel<0><<<512, NTH, 0, stream>>>(x, inwb, mh_conv_w, mh_conv_b,
      mh_dt_bias, mh_A_log, mh_D, Wcb, fc_b, out);
  mamba_dir_kernel<1><<<512, NTH, 0, stream>>>(x, inwb + 299008, mv_conv_w, mv_conv_b,
      mv_dt_bias, mv_A_log, mv_D, Wcb + 131072, fc_b, out);
}